// Round 4
// baseline (620.372 us; speedup 1.0000x reference)
//
#include <hip/hip_runtime.h>
#include <hip/hip_bf16.h>

// Problem geometry
#define N_ROWS 32000   // Q_OUT*Q_IN*NUM_P
#define SB     12      // SCALAR_BASIS
#define FC     720     // FILTER_C
#define FD     2704    // FILTER_DIM
#define KST    2752    // FD padded to 43*64 (BK=64 tiles)
#define NT     43      // K tiles
#define OCOLS  2704    // DIM_OUT*DIM_IN
#define OPAD   2816    // OCOLS padded to 11*256
#define ANGD   25
#define NTILES 1375    // 125 bm * 11 bn
#define GEMM_BLOCKS 256

typedef __attribute__((ext_vector_type(8))) short bf16x8;
typedef __attribute__((ext_vector_type(4))) float f32x4;

__device__ __forceinline__ void gload16(const void* g, void* l) {
    __builtin_amdgcn_global_load_lds(
        (const __attribute__((address_space(1))) void*)g,
        (__attribute__((address_space(3))) void*)l, 16, 0, 0);
}

__device__ __forceinline__ void decode_f(int f, int& c, int& j, int& a) {
    if (f < 144)       { c = f;                         j = 0;            a = 0;  }
    else if (f < 960)  { int t = f - 144;  c = 144 + t/3; j = t - (t/3)*3; a = 1;  }
    else if (f < 2000) { int t = f - 960;  c = 416 + t/5; j = t - (t/5)*5; a = 4;  }
    else if (f < 2560) { int t = f - 2000; c = 624 + t/7; j = t - (t/7)*7; a = 9;  }
    else               { int t = f - 2560; c = 704 + t/9; j = t - (t/9)*9; a = 16; }
}

// ---------------------------------------------------------------------------
// Kernel 1: 8 rows per block; W staged in LDS once per block (was: re-read
// 34.6 KB of W per row = 1.1 GB L2 traffic at 32000 blocks).
// sc = sk @ (W/sqrt(12)); filt[n, f] = sc[c(f)] * ang[a(f)+j(f)], bf16, KST.
// ---------------------------------------------------------------------------
#define RPB 8
__global__ __launch_bounds__(256) void build_filt(
    const float* __restrict__ sk,
    const float* __restrict__ ang,
    const float* __restrict__ W,
    __hip_bfloat16* __restrict__ filt)
{
    const int n0  = blockIdx.x * RPB;
    const int tid = threadIdx.x;  // 256
    __shared__ float s_W[SB * FC];        // 34560 B
    __shared__ float s_sc[RPB][FC];       // 23040 B
    __shared__ float s_ang[RPB * ANGD];   // 800 B
    __shared__ float s_sk[RPB * SB];      // 384 B

    for (int i = tid; i < SB * FC; i += 256) s_W[i] = W[i];
    if (tid < RPB * SB)   s_sk[tid]  = sk[(size_t)n0 * SB + tid];
    if (tid < RPB * ANGD) s_ang[tid] = ang[(size_t)n0 * ANGD + tid];
    __syncthreads();

    const float inv = 0.28867513459481288f; // 1/sqrt(12)
    for (int i = tid; i < RPB * FC; i += 256) {
        const int r = i / FC;
        const int c = i - r * FC;
        float acc = 0.f;
        #pragma unroll
        for (int s = 0; s < SB; ++s) acc += s_sk[r * SB + s] * s_W[s * FC + c];
        s_sc[r][c] = acc * inv;
    }
    __syncthreads();

    const int GP = KST / 8;  // 344 groups per row
    for (int gi = tid; gi < RPB * GP; gi += 256) {
        const int r  = gi / GP;
        const int f0 = (gi - r * GP) * 8;
        alignas(16) __hip_bfloat16 tmp[8];
        #pragma unroll
        for (int u = 0; u < 8; ++u) {
            const int f = f0 + u;
            float v = 0.f;
            if (f < FD) {
                int c, j, a;
                decode_f(f, c, j, a);
                v = s_sc[r][c] * s_ang[r * ANGD + a + j];
            }
            tmp[u] = __float2bfloat16(v);
        }
        *(bf16x8*)(filt + (size_t)(n0 + r) * KST + f0) = *(const bf16x8*)tmp;
    }
}

// ---------------------------------------------------------------------------
// Kernel 2: TP_mixing (2704x2704 f32) -> bf16 padded (OPAD x KST), pad = 0
// ---------------------------------------------------------------------------
#define GPR (KST / 8)   // 344 groups per row
__global__ void cvt_M(const float* __restrict__ M, __hip_bfloat16* __restrict__ out)
{
    const int g = blockIdx.x * 256 + threadIdx.x;
    if (g >= OPAD * GPR) return;
    const int o = g / GPR;
    const int k = (g - o * GPR) * 8;
    alignas(16) __hip_bfloat16 tmp[8];
    if (o < OCOLS && k + 8 <= FD) {
        const float4* p = (const float4*)(M + (size_t)o * FD + k);
        float4 x0 = p[0], x1 = p[1];
        tmp[0] = __float2bfloat16(x0.x); tmp[1] = __float2bfloat16(x0.y);
        tmp[2] = __float2bfloat16(x0.z); tmp[3] = __float2bfloat16(x0.w);
        tmp[4] = __float2bfloat16(x1.x); tmp[5] = __float2bfloat16(x1.y);
        tmp[6] = __float2bfloat16(x1.z); tmp[7] = __float2bfloat16(x1.w);
    } else {
        #pragma unroll
        for (int u = 0; u < 8; ++u) {
            float v = (o < OCOLS && k + u < FD) ? M[(size_t)o * FD + k + u] : 0.f;
            tmp[u] = __float2bfloat16(v);
        }
    }
    *(bf16x8*)(out + (size_t)o * KST + k) = *(const bf16x8*)tmp;
}

// ---------------------------------------------------------------------------
// Kernel 3: persistent 256x256-tile 8-phase bf16 GEMM (m201 structure).
// Round-robin strided tile assignment: block lb does tiles lb, lb+256, ...
// -> at step s all blocks cover tiles [256s,256s+256): ~23 shared A panels
// (33 MB, L3-resident) instead of 256 distinct ones. XCD chunking maps each
// XCD's 32 blocks onto 32 contiguous tiles (~4.3 MB A window ~ L2).
// ---------------------------------------------------------------------------
__global__ __launch_bounds__(512, 2) void gemm_bt(
    const __hip_bfloat16* __restrict__ A,
    const __hip_bfloat16* __restrict__ B,
    float* __restrict__ C)
{
    __shared__ __align__(1024) char lds[131072];
    char* const ldsA = lds;           // 2 buf x 2 half x 16384 B
    char* const ldsB = lds + 65536;

    const int tid  = threadIdx.x;
    const int wave = tid >> 6;
    const int lane = tid & 63;
    const int b    = blockIdx.x;
    // hw XCD assignment is round-robin on blockIdx: XCD x owns logical chunk
    // [x*32, x*32+32) -> 32 contiguous tiles per XCD per step.
    const int lb   = (b & 7) * 32 + (b >> 3);

    const int wr = wave >> 2;   // 0..1 (M)
    const int wc = wave & 3;    // 0..3 (N)

    // staging lane constants (LDS linear dest; source pre-swizzled)
    const int lrow  = lane >> 3;
    const int lslot = ((lane & 7) ^ (lrow & 7)) << 4;

    // reader lane constants
    const int rl   = lane & 15;
    const int koct = lane >> 4;
    const int sK0 = ((0 * 4 + koct) ^ (lane & 7)) << 4;
    const int sK1 = ((1 * 4 + koct) ^ (lane & 7)) << 4;
    const int arow = wr * 64 + rl;
    const int brow = (wc & 1) * 64 + rl;
    const int bhalf = wc >> 1;

    size_t arow0, brow0;
    auto SET_TILE = [&](int wg) {
        const int bm = wg / 11;
        const int bn = wg - bm * 11;
        arow0 = (size_t)bm * 256;
        brow0 = (size_t)bn * 256;
    };
    auto STAGE = [&](const char* gbase, size_t growbase, int tile, char* lbase) {
        const char* g0 = gbase + (growbase + (size_t)(wave * 8 + lrow)) * (KST * 2)
                               + (size_t)tile * 128 + lslot;
        gload16(g0,                          lbase + wave * 1024);
        gload16(g0 + (size_t)64 * (KST * 2), lbase + 8192 + wave * 1024);
    };
    // prologue: tile0 {B0,B1,A0,A1}, tile1 {B0,B1,A0}  (7 half-tiles)
    auto PROLOGUE = [&]() {
        STAGE((const char*)B, brow0 + 0,   0, ldsB + 0);
        STAGE((const char*)B, brow0 + 128, 0, ldsB + 16384);
        STAGE((const char*)A, arow0 + 0,   0, ldsA + 0);
        STAGE((const char*)A, arow0 + 128, 0, ldsA + 16384);
        STAGE((const char*)B, brow0 + 0,   1, ldsB + 32768);
        STAGE((const char*)B, brow0 + 128, 1, ldsB + 32768 + 16384);
        STAGE((const char*)A, arow0 + 0,   1, ldsA + 32768);
    };

    SET_TILE(lb);
    PROLOGUE();
    asm volatile("s_waitcnt vmcnt(6)" ::: "memory");
    __builtin_amdgcn_s_barrier();

    for (int wg = lb; wg < NTILES; wg += GEMM_BLOCKS) {
        SET_TILE(wg);
        f32x4 acc[8][4] = {};   // [q*2+m][n]

        for (int t = 0; t < NT; ++t) {
            char* const aB  = ldsA + (t & 1) * 32768;
            char* const bB  = ldsB + (t & 1) * 32768;
            char* const aBn = ldsA + ((t + 1) & 1) * 32768;

            bf16x8 bfr[4][2];
            #pragma unroll
            for (int q = 0; q < 4; ++q) {
                asm volatile("" ::: "memory");
                __builtin_amdgcn_sched_barrier(0);

                bf16x8 af[2][2];
                char* ah = aB + (q >> 1) * 16384;
                #pragma unroll
                for (int m = 0; m < 2; ++m) {
                    const int r = arow + (q & 1) * 32 + m * 16;
                    af[m][0] = *(const bf16x8*)(ah + r * 128 + sK0);
                    af[m][1] = *(const bf16x8*)(ah + r * 128 + sK1);
                }
                if (q == 0) {
                    char* bh = bB + bhalf * 16384;
                    #pragma unroll
                    for (int n = 0; n < 4; ++n) {
                        bfr[n][0] = *(const bf16x8*)(bh + (brow + n * 16) * 128 + sK0);
                        bfr[n][1] = *(const bf16x8*)(bh + (brow + n * 16) * 128 + sK1);
                    }
                }

                if (q == 0 && t + 1 < NT) STAGE((const char*)A, arow0 + 128, t + 1, aBn + 16384);
                if (q == 1 && t + 2 < NT) STAGE((const char*)B, brow0 + 0,   t + 2, bB + 0);
                if (q == 2 && t + 2 < NT) STAGE((const char*)B, brow0 + 128, t + 2, bB + 16384);
                if (q == 3 && t + 2 < NT) STAGE((const char*)A, arow0 + 0,   t + 2, aB + 0);

                __builtin_amdgcn_s_barrier();
                asm volatile("s_waitcnt lgkmcnt(0)" ::: "memory");
                __builtin_amdgcn_sched_barrier(0);

                __builtin_amdgcn_s_setprio(1);
                #pragma unroll
                for (int ks = 0; ks < 2; ++ks)
                    #pragma unroll
                    for (int m = 0; m < 2; ++m)
                        #pragma unroll
                        for (int n = 0; n < 4; ++n)
                            acc[q * 2 + m][n] = __builtin_amdgcn_mfma_f32_16x16x32_bf16(
                                af[m][ks], bfr[n][ks], acc[q * 2 + m][n], 0, 0, 0);
                __builtin_amdgcn_s_setprio(0);
                __builtin_amdgcn_sched_barrier(0);

                if (q == 3 && t + 1 < NT) {
                    if (t + 1 == NT - 1) asm volatile("s_waitcnt vmcnt(0)" ::: "memory");
                    else                 asm volatile("s_waitcnt vmcnt(6)" ::: "memory");
                }
                __builtin_amdgcn_s_barrier();
            }
        }

        // ---- inter-tile junction: issue next tile's prologue loads FIRST,
        // then this tile's epilogue stores overlap the load flight. vmcnt
        // retires in issue order, so vmcnt(6) leaves only trailing stores
        // outstanding -> all prologue loads complete. ----
        const int  nwg = wg + GEMM_BLOCKS;
        const bool has_next = (nwg < NTILES);
        const int  ocol0  = (int)brow0 + wc * 64 + rl;
        const int  orow_l = (lane >> 4) << 2;
        const int  arow0_c = (int)arow0;

        if (has_next) { SET_TILE(nwg); PROLOGUE(); }

        #pragma unroll
        for (int q = 0; q < 4; ++q)
            #pragma unroll
            for (int m = 0; m < 2; ++m) {
                const int grow = arow0_c + (q >> 1) * 128 + wr * 64 + (q & 1) * 32 + m * 16 + orow_l;
                #pragma unroll
                for (int n = 0; n < 4; ++n) {
                    const int gcol = ocol0 + n * 16;
                    if (gcol < OCOLS) {
                        #pragma unroll
                        for (int r = 0; r < 4; ++r)
                            C[(size_t)(grow + r) * OCOLS + gcol] = acc[q * 2 + m][n][r];
                    }
                }
            }

        if (has_next) {
            asm volatile("s_waitcnt vmcnt(6)" ::: "memory");
            __builtin_amdgcn_s_barrier();
        }
    }
}

// ---------------------------------------------------------------------------
extern "C" void kernel_launch(void* const* d_in, const int* in_sizes, int n_in,
                              void* d_out, int out_size, void* d_ws, size_t ws_size,
                              hipStream_t stream)
{
    const float* sk  = (const float*)d_in[0];
    const float* ang = (const float*)d_in[1];
    const float* W   = (const float*)d_in[2];
    const float* TP  = (const float*)d_in[3];
    float* out = (float*)d_out;

    __hip_bfloat16* filt = (__hip_bfloat16*)d_ws;           // N_ROWS*KST bf16
    __hip_bfloat16* Mb   = filt + (size_t)N_ROWS * KST;     // OPAD*KST bf16
    // ws needed: (32000*2752 + 2816*2752)*2 B ~= 192 MiB

    build_filt<<<N_ROWS / RPB, 256, 0, stream>>>(sk, ang, W, filt);

    const int totG = OPAD * GPR;
    cvt_M<<<(totG + 255) / 256, 256, 0, stream>>>(TP, Mb);

    gemm_bt<<<GEMM_BLOCKS, 512, 0, stream>>>(filt, Mb, out);
}

// Round 5
// 550.025 us; speedup vs baseline: 1.1279x; 1.1279x over previous
//
#include <hip/hip_runtime.h>
#include <hip/hip_bf16.h>

// Problem geometry
#define N_ROWS 32000   // Q_OUT*Q_IN*NUM_P
#define SB     12      // SCALAR_BASIS
#define FC     720     // FILTER_C
#define FD     2704    // FILTER_DIM
#define KST    2752    // FD padded to 43*64 (BK=64 tiles)
#define NT     43      // K tiles
#define OCOLS  2704    // DIM_OUT*DIM_IN
#define OPAD   2816    // OCOLS padded to 11*256
#define ANGD   25
#define NTILES 1375    // 125 bm * 11 bn
#define GEMM_BLOCKS 256

typedef __attribute__((ext_vector_type(8))) short bf16x8;
typedef __attribute__((ext_vector_type(4))) float f32x4;

__device__ __forceinline__ void gload16(const void* g, void* l) {
    __builtin_amdgcn_global_load_lds(
        (const __attribute__((address_space(1))) void*)g,
        (__attribute__((address_space(3))) void*)l, 16, 0, 0);
}

// ---------------------------------------------------------------------------
// Kernel 1: per-row n, sc = sk @ (W/sqrt(12)); expand to bf16 filt row (KST)
// (round-2 version: known-good 58 µs prep together with cvt_M)
// ---------------------------------------------------------------------------
__global__ void build_filt(const float* __restrict__ sk,
                           const float* __restrict__ ang,
                           const float* __restrict__ W,
                           __hip_bfloat16* __restrict__ filt)
{
    const int n   = blockIdx.x;
    const int tid = threadIdx.x;  // 256
    __shared__ float s_sc[FC];
    __shared__ float s_ang[ANGD];
    __shared__ float s_sk[SB];

    if (tid < SB) s_sk[tid] = sk[(size_t)n * SB + tid];
    if (tid >= 32 && tid < 32 + ANGD) s_ang[tid - 32] = ang[(size_t)n * ANGD + (tid - 32)];
    __syncthreads();

    const float inv = 0.28867513459481288f; // 1/sqrt(12)
    for (int c = tid; c < FC; c += 256) {
        float acc = 0.f;
        #pragma unroll
        for (int s = 0; s < SB; ++s) acc += s_sk[s] * W[s * FC + c];
        s_sc[c] = acc * inv;
    }
    __syncthreads();

    const size_t base = (size_t)n * KST;
    for (int f = tid; f < KST; f += 256) {
        float v = 0.f;
        if (f < FD) {
            int c, j, a;
            if (f < 144)       { c = f;                         j = 0;            a = 0;  }
            else if (f < 960)  { int t = f - 144;  c = 144 + t/3; j = t - (t/3)*3; a = 1;  }
            else if (f < 2000) { int t = f - 960;  c = 416 + t/5; j = t - (t/5)*5; a = 4;  }
            else if (f < 2560) { int t = f - 2000; c = 624 + t/7; j = t - (t/7)*7; a = 9;  }
            else               { int t = f - 2560; c = 704 + t/9; j = t - (t/9)*9; a = 16; }
            v = s_sc[c] * s_ang[a + j];
        }
        filt[base + f] = __float2bfloat16(v);
    }
}

// ---------------------------------------------------------------------------
// Kernel 2: TP_mixing (2704x2704 f32) -> bf16 padded (OPAD x KST), pad = 0
// (round-2 scalar version)
// ---------------------------------------------------------------------------
__global__ void cvt_M(const float* __restrict__ M, __hip_bfloat16* __restrict__ out)
{
    int idx = blockIdx.x * 256 + threadIdx.x;
    const int total = OPAD * KST;
    if (idx >= total) return;
    int o = idx / KST;
    int k = idx - o * KST;
    float v = (o < OCOLS && k < FD) ? M[(size_t)o * FD + k] : 0.f;
    out[idx] = __float2bfloat16(v);
}

// ---------------------------------------------------------------------------
// Kernel 3: persistent 256x256-tile 8-phase bf16 GEMM (m201 structure).
// Round-robin strided tiles (block lb: lb, lb+256, ...) + XCD chunking.
// SWAPPED MFMA operands -> D = C^T fragment (row=o, col=M) -> float4 C
// stores. Junction: PROLOGUE loads, then stores, then vmcnt(38) (= wait
// only tile0's 8 loads; stores + tile1 loads drain under t=0 compute).
// ---------------------------------------------------------------------------
__global__ __launch_bounds__(512, 2) void gemm_bt(
    const __hip_bfloat16* __restrict__ A,
    const __hip_bfloat16* __restrict__ B,
    float* __restrict__ C)
{
    __shared__ __align__(1024) char lds[131072];
    char* const ldsA = lds;           // 2 buf x 2 half x 16384 B
    char* const ldsB = lds + 65536;

    const int tid  = threadIdx.x;
    const int wave = tid >> 6;
    const int lane = tid & 63;
    const int b    = blockIdx.x;
    // XCD chunking: XCD x owns logical tiles [x*32, x*32+32) per step.
    const int lb   = (b & 7) * 32 + (b >> 3);

    const int wr = wave >> 2;   // 0..1 (M)
    const int wc = wave & 3;    // 0..3 (N)

    // staging lane constants (LDS linear dest; source pre-swizzled)
    const int lrow  = lane >> 3;
    const int lslot = ((lane & 7) ^ (lrow & 7)) << 4;

    // reader lane constants
    const int rl   = lane & 15;
    const int koct = lane >> 4;
    const int sK0 = ((0 * 4 + koct) ^ (lane & 7)) << 4;
    const int sK1 = ((1 * 4 + koct) ^ (lane & 7)) << 4;
    const int arow = wr * 64 + rl;
    const int brow = (wc & 1) * 64 + rl;
    const int bhalf = wc >> 1;

    size_t arow0, brow0;
    auto SET_TILE = [&](int wg) {
        const int bm = wg / 11;
        const int bn = wg - bm * 11;
        arow0 = (size_t)bm * 256;
        brow0 = (size_t)bn * 256;
    };
    auto STAGE = [&](const char* gbase, size_t growbase, int tile, char* lbase) {
        const char* g0 = gbase + (growbase + (size_t)(wave * 8 + lrow)) * (KST * 2)
                               + (size_t)tile * 128 + lslot;
        gload16(g0,                          lbase + wave * 1024);
        gload16(g0 + (size_t)64 * (KST * 2), lbase + 8192 + wave * 1024);
    };
    // prologue: tile0 {B0,B1,A0,A1}, tile1 {B0,B1,A0}  (7 half-tiles, 14 loads)
    auto PROLOGUE = [&]() {
        STAGE((const char*)B, brow0 + 0,   0, ldsB + 0);
        STAGE((const char*)B, brow0 + 128, 0, ldsB + 16384);
        STAGE((const char*)A, arow0 + 0,   0, ldsA + 0);
        STAGE((const char*)A, arow0 + 128, 0, ldsA + 16384);
        STAGE((const char*)B, brow0 + 0,   1, ldsB + 32768);
        STAGE((const char*)B, brow0 + 128, 1, ldsB + 32768 + 16384);
        STAGE((const char*)A, arow0 + 0,   1, ldsA + 32768);
    };

    SET_TILE(lb);
    PROLOGUE();
    asm volatile("s_waitcnt vmcnt(6)" ::: "memory");
    __builtin_amdgcn_s_barrier();

    for (int wg = lb; wg < NTILES; wg += GEMM_BLOCKS) {
        SET_TILE(wg);
        f32x4 acc[8][4] = {};   // [q*2+m][n]; D^T frags: row=o, col=M

        for (int t = 0; t < NT; ++t) {
            char* const aB  = ldsA + (t & 1) * 32768;
            char* const bB  = ldsB + (t & 1) * 32768;
            char* const aBn = ldsA + ((t + 1) & 1) * 32768;

            bf16x8 bfr[4][2];
            #pragma unroll
            for (int q = 0; q < 4; ++q) {
                asm volatile("" ::: "memory");
                __builtin_amdgcn_sched_barrier(0);

                bf16x8 af[2][2];
                char* ah = aB + (q >> 1) * 16384;
                #pragma unroll
                for (int m = 0; m < 2; ++m) {
                    const int r = arow + (q & 1) * 32 + m * 16;
                    af[m][0] = *(const bf16x8*)(ah + r * 128 + sK0);
                    af[m][1] = *(const bf16x8*)(ah + r * 128 + sK1);
                }
                if (q == 0) {
                    char* bh = bB + bhalf * 16384;
                    #pragma unroll
                    for (int n = 0; n < 4; ++n) {
                        bfr[n][0] = *(const bf16x8*)(bh + (brow + n * 16) * 128 + sK0);
                        bfr[n][1] = *(const bf16x8*)(bh + (brow + n * 16) * 128 + sK1);
                    }
                }

                if (q == 0 && t + 1 < NT) STAGE((const char*)A, arow0 + 128, t + 1, aBn + 16384);
                if (q == 1 && t + 2 < NT) STAGE((const char*)B, brow0 + 0,   t + 2, bB + 0);
                if (q == 2 && t + 2 < NT) STAGE((const char*)B, brow0 + 128, t + 2, bB + 16384);
                if (q == 3 && t + 2 < NT) STAGE((const char*)A, arow0 + 0,   t + 2, aB + 0);

                __builtin_amdgcn_s_barrier();
                asm volatile("s_waitcnt lgkmcnt(0)" ::: "memory");
                __builtin_amdgcn_sched_barrier(0);

                __builtin_amdgcn_s_setprio(1);
                #pragma unroll
                for (int ks = 0; ks < 2; ++ks)
                    #pragma unroll
                    for (int m = 0; m < 2; ++m)
                        #pragma unroll
                        for (int n = 0; n < 4; ++n)
                            acc[q * 2 + m][n] = __builtin_amdgcn_mfma_f32_16x16x32_bf16(
                                bfr[n][ks], af[m][ks], acc[q * 2 + m][n], 0, 0, 0);
                __builtin_amdgcn_s_setprio(0);
                __builtin_amdgcn_sched_barrier(0);

                if (q == 3 && t + 1 < NT) {
                    if (t + 1 == NT - 1) asm volatile("s_waitcnt vmcnt(0)" ::: "memory");
                    else                 asm volatile("s_waitcnt vmcnt(6)" ::: "memory");
                }
                __builtin_amdgcn_s_barrier();
            }
        }

        // ---- junction: next-tile prologue loads FIRST, then C^T-frag
        // float4 stores; vmcnt(38) waits ONLY tile0's 8 loads (14+32-38=8),
        // leaving 6 tile1-loads + 32 stores in flight (drained by t=0 q=3
        // vmcnt(6) under compute). ----
        const int  nwg = wg + GEMM_BLOCKS;
        const bool has_next = (nwg < NTILES);
        const int  arow0_c = (int)arow0;
        const int  obase0  = (int)brow0 + wc * 64 + koct * 4;

        if (has_next) { SET_TILE(nwg); PROLOGUE(); }

        // D: row=o=(lane>>4)*4+r, col=M=lane&15 -> lane stores float4 at
        // C[M*OCOLS + o], o quad-aligned, OCOLS%4==0 -> aligned 16B.
        #pragma unroll
        for (int q = 0; q < 4; ++q)
            #pragma unroll
            for (int m = 0; m < 2; ++m) {
                const int Mrow = arow0_c + (q >> 1) * 128 + wr * 64 + (q & 1) * 32 + m * 16 + rl;
                #pragma unroll
                for (int n = 0; n < 4; ++n) {
                    const int o = obase0 + n * 16;
                    if (o < OCOLS)
                        *(f32x4*)(C + (size_t)Mrow * OCOLS + o) = acc[q * 2 + m][n];
                }
            }

        if (has_next) {
            asm volatile("s_waitcnt vmcnt(38)" ::: "memory");
            __builtin_amdgcn_s_barrier();
        }
    }
}

// ---------------------------------------------------------------------------
extern "C" void kernel_launch(void* const* d_in, const int* in_sizes, int n_in,
                              void* d_out, int out_size, void* d_ws, size_t ws_size,
                              hipStream_t stream)
{
    const float* sk  = (const float*)d_in[0];
    const float* ang = (const float*)d_in[1];
    const float* W   = (const float*)d_in[2];
    const float* TP  = (const float*)d_in[3];
    float* out = (float*)d_out;

    __hip_bfloat16* filt = (__hip_bfloat16*)d_ws;           // N_ROWS*KST bf16
    __hip_bfloat16* Mb   = filt + (size_t)N_ROWS * KST;     // OPAD*KST bf16
    // ws needed: (32000*2752 + 2816*2752)*2 B ~= 192 MiB

    build_filt<<<N_ROWS, 256, 0, stream>>>(sk, ang, W, filt);

    const int totM = OPAD * KST;
    cvt_M<<<(totM + 255) / 256, 256, 0, stream>>>(TP, Mb);

    gemm_bt<<<GEMM_BLOCKS, 512, 0, stream>>>(filt, Mb, out);
}

// Round 6
// 190.756 us; speedup vs baseline: 3.2522x; 2.8834x over previous
//
#include <hip/hip_runtime.h>
#include <hip/hip_bf16.h>

// Problem geometry
#define N_ROWS 32000   // Q_OUT*Q_IN*NUM_P
#define SB     12      // SCALAR_BASIS
#define FC     720     // FILTER_C
#define FD     2704    // FILTER_DIM
#define OCOLS  2704    // DIM_OUT*DIM_IN
#define OPAD   2816    // OCOLS padded to 11*256
#define ANGD   25
#define PDIM   300     // SB * ANGD
#define KST    320     // PDIM padded to 5*64
#define NT     5       // K tiles of 64
#define NTILES 1375    // 125 bm * 11 bn
#define GEMM_BLOCKS 256

typedef __attribute__((ext_vector_type(8))) short bf16x8;
typedef __attribute__((ext_vector_type(4))) float f32x4;

__device__ __forceinline__ void gload16(const void* g, void* l) {
    __builtin_amdgcn_global_load_lds(
        (const __attribute__((address_space(1))) void*)g,
        (__attribute__((address_space(3))) void*)l, 16, 0, 0);
}

// ---------------------------------------------------------------------------
// Kernel A: V[o, s*25+alpha] = sum_c TP[o, off_l + c*m_l + (alpha-a_l)]
//                                  * (W[s, sc_l + c] / sqrt(12))
// One block per padded o row (2816); rows >= 2704 and p >= 300 are zeros.
// LDS: TP row (10.8 KB) + scaled W (34.6 KB).
// ---------------------------------------------------------------------------
__global__ __launch_bounds__(256) void build_V(
    const float* __restrict__ TP,
    const float* __restrict__ W,
    __hip_bfloat16* __restrict__ V)
{
    const int o   = blockIdx.x;   // 0..OPAD-1
    const int tid = threadIdx.x;
    __shared__ float s_tp[FD];        // 10816 B
    __shared__ float s_w[SB * FC];    // 34560 B

    const float inv = 0.28867513459481288f; // 1/sqrt(12)
    for (int i = tid; i < SB * FC; i += 256) s_w[i] = W[i] * inv;
    if (o < OCOLS) {
        for (int i = tid; i < FD; i += 256) s_tp[i] = TP[(size_t)o * FD + i];
    } else {
        for (int i = tid; i < FD; i += 256) s_tp[i] = 0.f;
    }
    __syncthreads();

    for (int p = tid; p < KST; p += 256) {
        float acc = 0.f;
        if (p < PDIM) {
            const int s     = p / ANGD;
            const int alpha = p - s * ANGD;
            int m, off, sco, al, Cl;
            if (alpha < 1)       { m = 1; off = 0;    sco = 0;   al = 0;  Cl = 144; }
            else if (alpha < 4)  { m = 3; off = 144;  sco = 144; al = 1;  Cl = 272; }
            else if (alpha < 9)  { m = 5; off = 960;  sco = 416; al = 4;  Cl = 208; }
            else if (alpha < 16) { m = 7; off = 2000; sco = 624; al = 9;  Cl = 80;  }
            else                 { m = 9; off = 2560; sco = 704; al = 16; Cl = 16;  }
            const int j = alpha - al;
            const float* tp = s_tp + off + j;
            const float* ww = s_w + s * FC + sco;
            for (int c = 0; c < Cl; ++c) acc += tp[c * m] * ww[c];
        }
        V[(size_t)o * KST + p] = __float2bfloat16(acc);
    }
}

// ---------------------------------------------------------------------------
// Kernel B: X[n, s*25+alpha] = sk[n,s] * ang[n,alpha], bf16, padded to KST.
// Thread handles 8 consecutive p (one bf16x8 store). 40 groups per row.
// ---------------------------------------------------------------------------
__global__ void build_X(const float* __restrict__ sk,
                        const float* __restrict__ ang,
                        __hip_bfloat16* __restrict__ X)
{
    const int idx = blockIdx.x * 256 + threadIdx.x;
    if (idx >= N_ROWS * (KST / 8)) return;
    const int n  = idx / (KST / 8);
    const int p0 = (idx - n * (KST / 8)) * 8;
    const float* skn  = sk  + (size_t)n * SB;
    const float* angn = ang + (size_t)n * ANGD;
    alignas(16) __hip_bfloat16 tmp[8];
    #pragma unroll
    for (int u = 0; u < 8; ++u) {
        const int p = p0 + u;
        float v = 0.f;
        if (p < PDIM) {
            const int s = p / ANGD;
            const int a = p - s * ANGD;
            v = skn[s] * angn[a];
        }
        tmp[u] = __float2bfloat16(v);
    }
    *(bf16x8*)(X + (size_t)n * KST + p0) = *(const bf16x8*)tmp;
}

// ---------------------------------------------------------------------------
// Kernel C: persistent 256x256-tile 8-phase bf16 GEMM (round-5 structure,
// K=320). k[n,o] = sum_p X[n,p] V[o,p]. Swapped MFMA -> C^T frags ->
// float4 stores. Now output-write-bound (52 GFLOP, 346 MB C).
// ---------------------------------------------------------------------------
__global__ __launch_bounds__(512, 2) void gemm_bt(
    const __hip_bfloat16* __restrict__ A,   // X: (N_ROWS, KST)
    const __hip_bfloat16* __restrict__ B,   // V: (OPAD, KST)
    float* __restrict__ C)
{
    __shared__ __align__(1024) char lds[131072];
    char* const ldsA = lds;           // 2 buf x 2 half x 16384 B
    char* const ldsB = lds + 65536;

    const int tid  = threadIdx.x;
    const int wave = tid >> 6;
    const int lane = tid & 63;
    const int b    = blockIdx.x;
    // XCD chunking: XCD x owns logical tiles [x*32, x*32+32) per step.
    const int lb   = (b & 7) * 32 + (b >> 3);

    const int wr = wave >> 2;   // 0..1 (M)
    const int wc = wave & 3;    // 0..3 (N)

    // staging lane constants (LDS linear dest; source pre-swizzled)
    const int lrow  = lane >> 3;
    const int lslot = ((lane & 7) ^ (lrow & 7)) << 4;

    // reader lane constants
    const int rl   = lane & 15;
    const int koct = lane >> 4;
    const int sK0 = ((0 * 4 + koct) ^ (lane & 7)) << 4;
    const int sK1 = ((1 * 4 + koct) ^ (lane & 7)) << 4;
    const int arow = wr * 64 + rl;
    const int brow = (wc & 1) * 64 + rl;
    const int bhalf = wc >> 1;

    size_t arow0, brow0;
    auto SET_TILE = [&](int wg) {
        const int bm = wg / 11;
        const int bn = wg - bm * 11;
        arow0 = (size_t)bm * 256;
        brow0 = (size_t)bn * 256;
    };
    auto STAGE = [&](const char* gbase, size_t growbase, int tile, char* lbase) {
        const char* g0 = gbase + (growbase + (size_t)(wave * 8 + lrow)) * (KST * 2)
                               + (size_t)tile * 128 + lslot;
        gload16(g0,                          lbase + wave * 1024);
        gload16(g0 + (size_t)64 * (KST * 2), lbase + 8192 + wave * 1024);
    };
    // prologue: tile0 {B0,B1,A0,A1}, tile1 {B0,B1,A0}  (7 half-tiles, 14 loads)
    auto PROLOGUE = [&]() {
        STAGE((const char*)B, brow0 + 0,   0, ldsB + 0);
        STAGE((const char*)B, brow0 + 128, 0, ldsB + 16384);
        STAGE((const char*)A, arow0 + 0,   0, ldsA + 0);
        STAGE((const char*)A, arow0 + 128, 0, ldsA + 16384);
        STAGE((const char*)B, brow0 + 0,   1, ldsB + 32768);
        STAGE((const char*)B, brow0 + 128, 1, ldsB + 32768 + 16384);
        STAGE((const char*)A, arow0 + 0,   1, ldsA + 32768);
    };

    SET_TILE(lb);
    PROLOGUE();
    asm volatile("s_waitcnt vmcnt(6)" ::: "memory");
    __builtin_amdgcn_s_barrier();

    for (int wg = lb; wg < NTILES; wg += GEMM_BLOCKS) {
        SET_TILE(wg);
        f32x4 acc[8][4] = {};   // [q*2+m][n]; D^T frags: row=o, col=M

        for (int t = 0; t < NT; ++t) {
            char* const aB  = ldsA + (t & 1) * 32768;
            char* const bB  = ldsB + (t & 1) * 32768;
            char* const aBn = ldsA + ((t + 1) & 1) * 32768;

            bf16x8 bfr[4][2];
            #pragma unroll
            for (int q = 0; q < 4; ++q) {
                asm volatile("" ::: "memory");
                __builtin_amdgcn_sched_barrier(0);

                bf16x8 af[2][2];
                char* ah = aB + (q >> 1) * 16384;
                #pragma unroll
                for (int m = 0; m < 2; ++m) {
                    const int r = arow + (q & 1) * 32 + m * 16;
                    af[m][0] = *(const bf16x8*)(ah + r * 128 + sK0);
                    af[m][1] = *(const bf16x8*)(ah + r * 128 + sK1);
                }
                if (q == 0) {
                    char* bh = bB + bhalf * 16384;
                    #pragma unroll
                    for (int n = 0; n < 4; ++n) {
                        bfr[n][0] = *(const bf16x8*)(bh + (brow + n * 16) * 128 + sK0);
                        bfr[n][1] = *(const bf16x8*)(bh + (brow + n * 16) * 128 + sK1);
                    }
                }

                if (q == 0 && t + 1 < NT) STAGE((const char*)A, arow0 + 128, t + 1, aBn + 16384);
                if (q == 1 && t + 2 < NT) STAGE((const char*)B, brow0 + 0,   t + 2, bB + 0);
                if (q == 2 && t + 2 < NT) STAGE((const char*)B, brow0 + 128, t + 2, bB + 16384);
                if (q == 3 && t + 2 < NT) STAGE((const char*)A, arow0 + 0,   t + 2, aB + 0);

                __builtin_amdgcn_s_barrier();
                asm volatile("s_waitcnt lgkmcnt(0)" ::: "memory");
                __builtin_amdgcn_sched_barrier(0);

                __builtin_amdgcn_s_setprio(1);
                #pragma unroll
                for (int ks = 0; ks < 2; ++ks)
                    #pragma unroll
                    for (int m = 0; m < 2; ++m)
                        #pragma unroll
                        for (int n = 0; n < 4; ++n)
                            acc[q * 2 + m][n] = __builtin_amdgcn_mfma_f32_16x16x32_bf16(
                                bfr[n][ks], af[m][ks], acc[q * 2 + m][n], 0, 0, 0);
                __builtin_amdgcn_s_setprio(0);
                __builtin_amdgcn_sched_barrier(0);

                if (q == 3 && t + 1 < NT) {
                    if (t + 1 == NT - 1) asm volatile("s_waitcnt vmcnt(0)" ::: "memory");
                    else                 asm volatile("s_waitcnt vmcnt(6)" ::: "memory");
                }
                __builtin_amdgcn_s_barrier();
            }
        }

        // ---- junction: next-tile prologue loads FIRST, then C^T-frag
        // float4 stores; vmcnt(38) waits ONLY tile0's 8 loads (14+32-38=8),
        // leaving 6 tile1-loads + 32 stores in flight (drained by t=0 q=3
        // vmcnt(6) under compute). ----
        const int  nwg = wg + GEMM_BLOCKS;
        const bool has_next = (nwg < NTILES);
        const int  arow0_c = (int)arow0;
        const int  obase0  = (int)brow0 + wc * 64 + koct * 4;

        if (has_next) { SET_TILE(nwg); PROLOGUE(); }

        // D: row=o=(lane>>4)*4+r, col=M=lane&15 -> lane stores float4 at
        // C[M*OCOLS + o], o quad-aligned, OCOLS%4==0 -> aligned 16B.
        #pragma unroll
        for (int q = 0; q < 4; ++q)
            #pragma unroll
            for (int m = 0; m < 2; ++m) {
                const int Mrow = arow0_c + (q >> 1) * 128 + wr * 64 + (q & 1) * 32 + m * 16 + rl;
                #pragma unroll
                for (int n = 0; n < 4; ++n) {
                    const int o = obase0 + n * 16;
                    if (o < OCOLS)
                        *(f32x4*)(C + (size_t)Mrow * OCOLS + o) = acc[q * 2 + m][n];
                }
            }

        if (has_next) {
            asm volatile("s_waitcnt vmcnt(38)" ::: "memory");
            __builtin_amdgcn_s_barrier();
        }
    }
}

// ---------------------------------------------------------------------------
extern "C" void kernel_launch(void* const* d_in, const int* in_sizes, int n_in,
                              void* d_out, int out_size, void* d_ws, size_t ws_size,
                              hipStream_t stream)
{
    const float* sk  = (const float*)d_in[0];   // (16,16,125,12)
    const float* ang = (const float*)d_in[1];   // (32000,25)
    const float* W   = (const float*)d_in[2];   // (12,720)
    const float* TP  = (const float*)d_in[3];   // (2704,2704)
    float* out = (float*)d_out;                 // (32000,2704)

    __hip_bfloat16* X  = (__hip_bfloat16*)d_ws;             // N_ROWS*KST bf16 (20.5 MB)
    __hip_bfloat16* Vb = X + (size_t)N_ROWS * KST;          // OPAD*KST bf16 (1.8 MB)

    build_V<<<OPAD, 256, 0, stream>>>(TP, W, Vb);
    build_X<<<(N_ROWS * (KST / 8) + 255) / 256, 256, 0, stream>>>(sk, ang, X);
    gemm_bt<<<GEMM_BLOCKS, 512, 0, stream>>>(X, Vb, out);
}

// Round 7
// 185.944 us; speedup vs baseline: 3.3363x; 1.0259x over previous
//
#include <hip/hip_runtime.h>
#include <hip/hip_bf16.h>

// Problem geometry
#define N_ROWS 32000   // Q_OUT*Q_IN*NUM_P
#define SB     12      // SCALAR_BASIS
#define FC     720     // FILTER_C
#define FD     2704    // FILTER_DIM
#define OCOLS  2704    // DIM_OUT*DIM_IN
#define OPAD   2816    // OCOLS padded to 22*128
#define ANGD   25
#define PDIM   300     // SB * ANGD
#define KST    320     // PDIM padded to 5*64
#define NT     5       // K tiles of 64

typedef __attribute__((ext_vector_type(8))) short bf16x8;
typedef __attribute__((ext_vector_type(4))) float f32x4;

__device__ __forceinline__ void gload16(const void* g, void* l) {
    __builtin_amdgcn_global_load_lds(
        (const __attribute__((address_space(1))) void*)g,
        (__attribute__((address_space(3))) void*)l, 16, 0, 0);
}

// ---------------------------------------------------------------------------
// Kernel A: V[o, s*25+alpha] = sum_c TP[o, off_l + c*m_l + (alpha-a_l)]
//                                  * (W[s, sc_l + c] / sqrt(12))
// One block per padded o row (2816); rows >= 2704 and p >= 300 are zeros.
// ---------------------------------------------------------------------------
__global__ __launch_bounds__(256) void build_V(
    const float* __restrict__ TP,
    const float* __restrict__ W,
    __hip_bfloat16* __restrict__ V)
{
    const int o   = blockIdx.x;   // 0..OPAD-1
    const int tid = threadIdx.x;
    __shared__ float s_tp[FD];        // 10816 B
    __shared__ float s_w[SB * FC];    // 34560 B

    const float inv = 0.28867513459481288f; // 1/sqrt(12)
    for (int i = tid; i < SB * FC; i += 256) s_w[i] = W[i] * inv;
    if (o < OCOLS) {
        for (int i = tid; i < FD; i += 256) s_tp[i] = TP[(size_t)o * FD + i];
    } else {
        for (int i = tid; i < FD; i += 256) s_tp[i] = 0.f;
    }
    __syncthreads();

    for (int p = tid; p < KST; p += 256) {
        float acc = 0.f;
        if (p < PDIM) {
            const int s     = p / ANGD;
            const int alpha = p - s * ANGD;
            int m, off, sco, al, Cl;
            if (alpha < 1)       { m = 1; off = 0;    sco = 0;   al = 0;  Cl = 144; }
            else if (alpha < 4)  { m = 3; off = 144;  sco = 144; al = 1;  Cl = 272; }
            else if (alpha < 9)  { m = 5; off = 960;  sco = 416; al = 4;  Cl = 208; }
            else if (alpha < 16) { m = 7; off = 2000; sco = 624; al = 9;  Cl = 80;  }
            else                 { m = 9; off = 2560; sco = 704; al = 16; Cl = 16;  }
            const int j = alpha - al;
            const float* tp = s_tp + off + j;
            const float* ww = s_w + s * FC + sco;
            #pragma unroll 4
            for (int c = 0; c < Cl; ++c) acc += tp[c * m] * ww[c];
        }
        V[(size_t)o * KST + p] = __float2bfloat16(acc);
    }
}

// ---------------------------------------------------------------------------
// Kernel B: X[n, s*25+alpha] = sk[n,s] * ang[n,alpha], bf16, padded to KST.
// ---------------------------------------------------------------------------
__global__ void build_X(const float* __restrict__ sk,
                        const float* __restrict__ ang,
                        __hip_bfloat16* __restrict__ X)
{
    const int idx = blockIdx.x * 256 + threadIdx.x;
    if (idx >= N_ROWS * (KST / 8)) return;
    const int n  = idx / (KST / 8);
    const int p0 = (idx - n * (KST / 8)) * 8;
    const float* skn  = sk  + (size_t)n * SB;
    const float* angn = ang + (size_t)n * ANGD;
    alignas(16) __hip_bfloat16 tmp[8];
    #pragma unroll
    for (int u = 0; u < 8; ++u) {
        const int p = p0 + u;
        float v = 0.f;
        if (p < PDIM) {
            const int s = p / ANGD;
            const int a = p - s * ANGD;
            v = skn[s] * angn[a];
        }
        tmp[u] = __float2bfloat16(v);
    }
    *(bf16x8*)(X + (size_t)n * KST + p0) = *(const bf16x8*)tmp;
}

// ---------------------------------------------------------------------------
// Kernel C: 128x128-tile bf16 GEMM for the write-bound K=320 regime.
// k[n,o] = sum_p X[n,p] V[o,p]. 8 waves (2M x 4N), per-wave 64x32 out.
// BK=64, double-buffered LDS (64 KiB -> 2 blocks/CU, 16 waves/CU for
// store/compute overlap). XOR-swizzled STAGE + swizzled ds_read_b128
// (verified r2-r6 machinery). Swapped MFMA -> C^T frags -> f32x4 stores.
// ---------------------------------------------------------------------------
__global__ __launch_bounds__(512, 4) void gemm_bt(
    const __hip_bfloat16* __restrict__ A,   // X: (N_ROWS, KST)
    const __hip_bfloat16* __restrict__ B,   // V: (OPAD, KST)
    float* __restrict__ C)
{
    __shared__ __align__(1024) char lds[65536];
    char* const bufA = lds;            // 2 x 16384 B
    char* const bufB = lds + 32768;    // 2 x 16384 B

    const int tid  = threadIdx.x;
    const int wave = tid >> 6;
    const int lane = tid & 63;

    const int bn = blockIdx.x;         // 22 col tiles
    const int bm = blockIdx.y;         // 250 row tiles
    const size_t arow0 = (size_t)bm * 128;
    const size_t brow0 = (size_t)bn * 128;

    const int wr = wave >> 2;   // 0..1 (M half: 64 rows)
    const int wc = wave & 3;    // 0..3 (N quarter: 32 cols)

    // staging lane constants (LDS linear dest; global source pre-swizzled)
    const int lrow  = lane >> 3;
    const int lslot = ((lane & 7) ^ (lrow & 7)) << 4;

    // One STAGE = one [128 rows][64 cols] bf16 tile (16384 B):
    // 8 waves x rows {w*8+lrow, 64+w*8+lrow}, 16 B per lane per row.
    auto STAGE = [&](const char* gbase, size_t growbase, int t, char* lbase) {
        const char* g0 = gbase + (growbase + (size_t)(wave * 8 + lrow)) * (KST * 2)
                               + (size_t)t * 128 + lslot;
        gload16(g0,                          lbase + wave * 1024);
        gload16(g0 + (size_t)64 * (KST * 2), lbase + 8192 + wave * 1024);
    };

    // reader lane constants (swizzle: slot = (ks*4+koct) ^ (row&7), row&7==lane&7)
    const int rl   = lane & 15;
    const int koct = lane >> 4;
    const int sK0 = ((0 * 4 + koct) ^ (lane & 7)) << 4;
    const int sK1 = ((1 * 4 + koct) ^ (lane & 7)) << 4;

    // prologue: stage t0 into buf0, t1 into buf1 (8 loads/thread total)
    STAGE((const char*)A, arow0, 0, bufA + 0);
    STAGE((const char*)B, brow0, 0, bufB + 0);
    STAGE((const char*)A, arow0, 1, bufA + 16384);
    STAGE((const char*)B, brow0, 1, bufB + 16384);
    asm volatile("s_waitcnt vmcnt(4)" ::: "memory");
    __builtin_amdgcn_s_barrier();

    f32x4 acc[4][2] = {};   // [m][n]; D^T frags: row=o, col=M

    for (int t = 0; t < NT; ++t) {
        char* const aC = bufA + (t & 1) * 16384;
        char* const bC = bufB + (t & 1) * 16384;

        bf16x8 af[4][2], bfr[2][2];
        #pragma unroll
        for (int m = 0; m < 4; ++m) {
            const int r = wr * 64 + m * 16 + rl;
            af[m][0] = *(const bf16x8*)(aC + r * 128 + sK0);
            af[m][1] = *(const bf16x8*)(aC + r * 128 + sK1);
        }
        #pragma unroll
        for (int n = 0; n < 2; ++n) {
            const int r = wc * 32 + n * 16 + rl;
            bfr[n][0] = *(const bf16x8*)(bC + r * 128 + sK0);
            bfr[n][1] = *(const bf16x8*)(bC + r * 128 + sK1);
        }
        asm volatile("s_waitcnt lgkmcnt(0)" ::: "memory");
        __builtin_amdgcn_sched_barrier(0);
        __builtin_amdgcn_s_barrier();   // all waves done reading this buf

        if (t + 2 < NT) {               // stage t+2 into the buffer just read
            STAGE((const char*)A, arow0, t + 2, aC);
            STAGE((const char*)B, brow0, t + 2, bC);
        }

        __builtin_amdgcn_s_setprio(1);
        #pragma unroll
        for (int ks = 0; ks < 2; ++ks)
            #pragma unroll
            for (int m = 0; m < 4; ++m)
                #pragma unroll
                for (int n = 0; n < 2; ++n)
                    acc[m][n] = __builtin_amdgcn_mfma_f32_16x16x32_bf16(
                        bfr[n][ks], af[m][ks], acc[m][n], 0, 0, 0);
        __builtin_amdgcn_s_setprio(0);
        __builtin_amdgcn_sched_barrier(0);

        // ledger: after stage, outstanding = {t+1:4, t+2:4}; wait t+1 only.
        if (t < NT - 2)       asm volatile("s_waitcnt vmcnt(4)" ::: "memory");
        else if (t == NT - 2) asm volatile("s_waitcnt vmcnt(0)" ::: "memory");
        if (t < NT - 1) __builtin_amdgcn_s_barrier();
    }

    // epilogue: D^T frag -> lane stores f32x4 at C[M*OCOLS + o]
    // M = arow0 + wr*64 + m*16 + rl;  o = brow0 + wc*32 + n*16 + koct*4
    const int Mbase = (int)arow0 + wr * 64 + rl;
    const int obase = (int)brow0 + wc * 32 + koct * 4;
    #pragma unroll
    for (int m = 0; m < 4; ++m) {
        const int Mrow = Mbase + m * 16;
        #pragma unroll
        for (int n = 0; n < 2; ++n) {
            const int o = obase + n * 16;
            if (o < OCOLS)
                *(f32x4*)(C + (size_t)Mrow * OCOLS + o) = acc[m][n];
        }
    }
}

// ---------------------------------------------------------------------------
extern "C" void kernel_launch(void* const* d_in, const int* in_sizes, int n_in,
                              void* d_out, int out_size, void* d_ws, size_t ws_size,
                              hipStream_t stream)
{
    const float* sk  = (const float*)d_in[0];   // (16,16,125,12)
    const float* ang = (const float*)d_in[1];   // (32000,25)
    const float* W   = (const float*)d_in[2];   // (12,720)
    const float* TP  = (const float*)d_in[3];   // (2704,2704)
    float* out = (float*)d_out;                 // (32000,2704)

    __hip_bfloat16* X  = (__hip_bfloat16*)d_ws;             // N_ROWS*KST bf16 (20.5 MB)
    __hip_bfloat16* Vb = X + (size_t)N_ROWS * KST;          // OPAD*KST bf16 (1.8 MB)

    build_V<<<OPAD, 256, 0, stream>>>(TP, W, Vb);
    build_X<<<(N_ROWS * (KST / 8) + 255) / 256, 256, 0, stream>>>(sk, ang, X);

    dim3 grid(OPAD / 128, N_ROWS / 128);   // (22, 250)
    gemm_bt<<<grid, 512, 0, stream>>>(X, Vb, out);
}

// Round 8
// 178.424 us; speedup vs baseline: 3.4770x; 1.0421x over previous
//
#include <hip/hip_runtime.h>
#include <hip/hip_bf16.h>

// Problem geometry
#define N_ROWS 32000   // Q_OUT*Q_IN*NUM_P
#define SB     12      // SCALAR_BASIS
#define FC     720     // FILTER_C
#define FD     2704    // FILTER_DIM
#define OCOLS  2704    // DIM_OUT*DIM_IN
#define OPAD   2816    // OCOLS padded to 22*128
#define ANGD   25
#define PDIM   300     // SB * ANGD
#define KST    320     // PDIM padded to 5*64
#define NT     5       // K tiles of 64

typedef __attribute__((ext_vector_type(8))) short bf16x8;
typedef __attribute__((ext_vector_type(4))) float f32x4;

__device__ __forceinline__ void gload16(const void* g, void* l) {
    __builtin_amdgcn_global_load_lds(
        (const __attribute__((address_space(1))) void*)g,
        (__attribute__((address_space(3))) void*)l, 16, 0, 0);
}

// ---------------------------------------------------------------------------
// Kernel A: V[o, s*25+alpha] = sum_c TP[o, off_l + c*m_l + (alpha-a_l)]
//                                  * (W[s, sc_l + c] / sqrt(12))
// One block per padded o row (2816); rows >= 2704 and p >= 300 are zeros.
// ---------------------------------------------------------------------------
__global__ __launch_bounds__(256) void build_V(
    const float* __restrict__ TP,
    const float* __restrict__ W,
    __hip_bfloat16* __restrict__ V)
{
    const int o   = blockIdx.x;   // 0..OPAD-1
    const int tid = threadIdx.x;
    __shared__ float s_tp[FD];        // 10816 B
    __shared__ float s_w[SB * FC];    // 34560 B

    const float inv = 0.28867513459481288f; // 1/sqrt(12)
    for (int i = tid; i < SB * FC; i += 256) s_w[i] = W[i] * inv;
    if (o < OCOLS) {
        for (int i = tid; i < FD; i += 256) s_tp[i] = TP[(size_t)o * FD + i];
    } else {
        for (int i = tid; i < FD; i += 256) s_tp[i] = 0.f;
    }
    __syncthreads();

    for (int p = tid; p < KST; p += 256) {
        float acc = 0.f;
        if (p < PDIM) {
            const int s     = p / ANGD;
            const int alpha = p - s * ANGD;
            int m, off, sco, al, Cl;
            if (alpha < 1)       { m = 1; off = 0;    sco = 0;   al = 0;  Cl = 144; }
            else if (alpha < 4)  { m = 3; off = 144;  sco = 144; al = 1;  Cl = 272; }
            else if (alpha < 9)  { m = 5; off = 960;  sco = 416; al = 4;  Cl = 208; }
            else if (alpha < 16) { m = 7; off = 2000; sco = 624; al = 9;  Cl = 80;  }
            else                 { m = 9; off = 2560; sco = 704; al = 16; Cl = 16;  }
            const int j = alpha - al;
            const float* tp = s_tp + off + j;
            const float* ww = s_w + s * FC + sco;
            #pragma unroll 4
            for (int c = 0; c < Cl; ++c) acc += tp[c * m] * ww[c];
        }
        V[(size_t)o * KST + p] = __float2bfloat16(acc);
    }
}

// ---------------------------------------------------------------------------
// Kernel B: X[n, s*25+alpha] = sk[n,s] * ang[n,alpha], bf16, padded to KST.
// ---------------------------------------------------------------------------
__global__ void build_X(const float* __restrict__ sk,
                        const float* __restrict__ ang,
                        __hip_bfloat16* __restrict__ X)
{
    const int idx = blockIdx.x * 256 + threadIdx.x;
    if (idx >= N_ROWS * (KST / 8)) return;
    const int n  = idx / (KST / 8);
    const int p0 = (idx - n * (KST / 8)) * 8;
    const float* skn  = sk  + (size_t)n * SB;
    const float* angn = ang + (size_t)n * ANGD;
    alignas(16) __hip_bfloat16 tmp[8];
    #pragma unroll
    for (int u = 0; u < 8; ++u) {
        const int p = p0 + u;
        float v = 0.f;
        if (p < PDIM) {
            const int s = p / ANGD;
            const int a = p - s * ANGD;
            v = skn[s] * angn[a];
        }
        tmp[u] = __float2bfloat16(v);
    }
    *(bf16x8*)(X + (size_t)n * KST + p0) = *(const bf16x8*)tmp;
}

// ---------------------------------------------------------------------------
// Kernel C: 128x128-tile bf16 GEMM, write-bound K=320 regime.
// k[n,o] = sum_p X[n,p] V[o,p]. 8 waves (2M x 4N), per-wave 64x32 out.
// BK=64, double-buffered LDS (64 KiB -> 2 blocks/CU). Swapped MFMA ->
// C^T frags -> NONTEMPORAL f32x4 stores (C is write-once: bypass L2
// write-allocate, which was costing ~346 MB of hidden line-fill reads).
// ---------------------------------------------------------------------------
__global__ __launch_bounds__(512, 4) void gemm_bt(
    const __hip_bfloat16* __restrict__ A,   // X: (N_ROWS, KST)
    const __hip_bfloat16* __restrict__ B,   // V: (OPAD, KST)
    float* __restrict__ C)
{
    __shared__ __align__(1024) char lds[65536];
    char* const bufA = lds;            // 2 x 16384 B
    char* const bufB = lds + 32768;    // 2 x 16384 B

    const int tid  = threadIdx.x;
    const int wave = tid >> 6;
    const int lane = tid & 63;

    const int bn = blockIdx.x;         // 22 col tiles
    const int bm = blockIdx.y;         // 250 row tiles
    const size_t arow0 = (size_t)bm * 128;
    const size_t brow0 = (size_t)bn * 128;

    const int wr = wave >> 2;   // 0..1 (M half: 64 rows)
    const int wc = wave & 3;    // 0..3 (N quarter: 32 cols)

    // staging lane constants (LDS linear dest; global source pre-swizzled)
    const int lrow  = lane >> 3;
    const int lslot = ((lane & 7) ^ (lrow & 7)) << 4;

    // One STAGE = one [128 rows][64 cols] bf16 tile (16384 B)
    auto STAGE = [&](const char* gbase, size_t growbase, int t, char* lbase) {
        const char* g0 = gbase + (growbase + (size_t)(wave * 8 + lrow)) * (KST * 2)
                               + (size_t)t * 128 + lslot;
        gload16(g0,                          lbase + wave * 1024);
        gload16(g0 + (size_t)64 * (KST * 2), lbase + 8192 + wave * 1024);
    };

    // reader lane constants (swizzle: slot = (ks*4+koct) ^ (row&7))
    const int rl   = lane & 15;
    const int koct = lane >> 4;
    const int sK0 = ((0 * 4 + koct) ^ (lane & 7)) << 4;
    const int sK1 = ((1 * 4 + koct) ^ (lane & 7)) << 4;

    // prologue: stage t0 into buf0, t1 into buf1
    STAGE((const char*)A, arow0, 0, bufA + 0);
    STAGE((const char*)B, brow0, 0, bufB + 0);
    STAGE((const char*)A, arow0, 1, bufA + 16384);
    STAGE((const char*)B, brow0, 1, bufB + 16384);
    asm volatile("s_waitcnt vmcnt(4)" ::: "memory");
    __builtin_amdgcn_s_barrier();

    f32x4 acc[4][2] = {};   // [m][n]; D^T frags: row=o, col=M

    for (int t = 0; t < NT; ++t) {
        char* const aC = bufA + (t & 1) * 16384;
        char* const bC = bufB + (t & 1) * 16384;

        bf16x8 af[4][2], bfr[2][2];
        #pragma unroll
        for (int m = 0; m < 4; ++m) {
            const int r = wr * 64 + m * 16 + rl;
            af[m][0] = *(const bf16x8*)(aC + r * 128 + sK0);
            af[m][1] = *(const bf16x8*)(aC + r * 128 + sK1);
        }
        #pragma unroll
        for (int n = 0; n < 2; ++n) {
            const int r = wc * 32 + n * 16 + rl;
            bfr[n][0] = *(const bf16x8*)(bC + r * 128 + sK0);
            bfr[n][1] = *(const bf16x8*)(bC + r * 128 + sK1);
        }
        asm volatile("s_waitcnt lgkmcnt(0)" ::: "memory");
        __builtin_amdgcn_sched_barrier(0);
        __builtin_amdgcn_s_barrier();   // all waves done reading this buf

        if (t + 2 < NT) {               // stage t+2 into the buffer just read
            STAGE((const char*)A, arow0, t + 2, aC);
            STAGE((const char*)B, brow0, t + 2, bC);
        }

        __builtin_amdgcn_s_setprio(1);
        #pragma unroll
        for (int ks = 0; ks < 2; ++ks)
            #pragma unroll
            for (int m = 0; m < 4; ++m)
                #pragma unroll
                for (int n = 0; n < 2; ++n)
                    acc[m][n] = __builtin_amdgcn_mfma_f32_16x16x32_bf16(
                        bfr[n][ks], af[m][ks], acc[m][n], 0, 0, 0);
        __builtin_amdgcn_s_setprio(0);
        __builtin_amdgcn_sched_barrier(0);

        if (t < NT - 2)       asm volatile("s_waitcnt vmcnt(4)" ::: "memory");
        else if (t == NT - 2) asm volatile("s_waitcnt vmcnt(0)" ::: "memory");
        if (t < NT - 1) __builtin_amdgcn_s_barrier();
    }

    // epilogue: D^T frag -> nontemporal f32x4 at C[M*OCOLS + o]
    const int Mbase = (int)arow0 + wr * 64 + rl;
    const int obase = (int)brow0 + wc * 32 + koct * 4;
    #pragma unroll
    for (int m = 0; m < 4; ++m) {
        const int Mrow = Mbase + m * 16;
        #pragma unroll
        for (int n = 0; n < 2; ++n) {
            const int o = obase + n * 16;
            if (o < OCOLS)
                __builtin_nontemporal_store(acc[m][n],
                    (f32x4*)(C + (size_t)Mrow * OCOLS + o));
        }
    }
}

// ---------------------------------------------------------------------------
extern "C" void kernel_launch(void* const* d_in, const int* in_sizes, int n_in,
                              void* d_out, int out_size, void* d_ws, size_t ws_size,
                              hipStream_t stream)
{
    const float* sk  = (const float*)d_in[0];   // (16,16,125,12)
    const float* ang = (const float*)d_in[1];   // (32000,25)
    const float* W   = (const float*)d_in[2];   // (12,720)
    const float* TP  = (const float*)d_in[3];   // (2704,2704)
    float* out = (float*)d_out;                 // (32000,2704)

    __hip_bfloat16* X  = (__hip_bfloat16*)d_ws;             // N_ROWS*KST bf16 (20.5 MB)
    __hip_bfloat16* Vb = X + (size_t)N_ROWS * KST;          // OPAD*KST bf16 (1.8 MB)

    build_V<<<OPAD, 256, 0, stream>>>(TP, W, Vb);
    build_X<<<(N_ROWS * (KST / 8) + 255) / 256, 256, 0, stream>>>(sk, ang, X);

    dim3 grid(OPAD / 128, N_ROWS / 128);   // (22, 250)
    gemm_bt<<<grid, 512, 0, stream>>>(X, Vb, out);
}

// Round 9
// 156.916 us; speedup vs baseline: 3.9535x; 1.1371x over previous
//
#include <hip/hip_runtime.h>
#include <hip/hip_bf16.h>

// Problem geometry
#define N_ROWS 32000   // Q_OUT*Q_IN*NUM_P
#define SB     12      // SCALAR_BASIS
#define FC     720     // FILTER_C
#define FD     2704    // FILTER_DIM
#define OCOLS  2704    // DIM_OUT*DIM_IN
#define OPAD   2816    // OCOLS padded to 22*128
#define ANGD   25
#define PDIM   300     // SB * ANGD
#define KST    320     // PDIM padded to 5*64
#define NT     5       // K tiles of 64

typedef __attribute__((ext_vector_type(8))) short bf16x8;
typedef __attribute__((ext_vector_type(4))) float f32x4;

__device__ __forceinline__ void gload16(const void* g, void* l) {
    __builtin_amdgcn_global_load_lds(
        (const __attribute__((address_space(1))) void*)g,
        (__attribute__((address_space(3))) void*)l, 16, 0, 0);
}

// ---------------------------------------------------------------------------
// Kernel A v2: V[o, s*25+alpha] = sum_c TP[o, ...] * (W[s, ...]/sqrt(12)).
// 320 threads: one p per thread (5 waves, no double-duty). 4 independent
// accumulators break the FMA/LDS dependent chain (was latency-bound).
// All Cl in {144,272,208,80,16} are divisible by 4 -> no tail.
// ---------------------------------------------------------------------------
__global__ __launch_bounds__(320) void build_V(
    const float* __restrict__ TP,
    const float* __restrict__ W,
    __hip_bfloat16* __restrict__ V)
{
    const int o   = blockIdx.x;   // 0..OPAD-1
    const int tid = threadIdx.x;  // 0..319
    __shared__ float s_tp[FD];        // 10816 B
    __shared__ float s_w[SB * FC];    // 34560 B

    const float inv = 0.28867513459481288f; // 1/sqrt(12)
    for (int i = tid; i < SB * FC; i += 320) s_w[i] = W[i] * inv;
    if (o < OCOLS) {
        for (int i = tid; i < FD; i += 320) s_tp[i] = TP[(size_t)o * FD + i];
    } else {
        for (int i = tid; i < FD; i += 320) s_tp[i] = 0.f;
    }
    __syncthreads();

    const int p = tid;   // one p per thread
    float acc = 0.f;
    if (p < PDIM) {
        const int s     = p / ANGD;
        const int alpha = p - s * ANGD;
        int m, off, sco, al, Cl;
        if (alpha < 1)       { m = 1; off = 0;    sco = 0;   al = 0;  Cl = 144; }
        else if (alpha < 4)  { m = 3; off = 144;  sco = 144; al = 1;  Cl = 272; }
        else if (alpha < 9)  { m = 5; off = 960;  sco = 416; al = 4;  Cl = 208; }
        else if (alpha < 16) { m = 7; off = 2000; sco = 624; al = 9;  Cl = 80;  }
        else                 { m = 9; off = 2560; sco = 704; al = 16; Cl = 16;  }
        const int j = alpha - al;
        const float* tp = s_tp + off + j;
        const float* ww = s_w + s * FC + sco;
        float a0 = 0.f, a1 = 0.f, a2 = 0.f, a3 = 0.f;
        for (int c = 0; c < Cl; c += 4) {
            a0 += tp[(c + 0) * m] * ww[c + 0];
            a1 += tp[(c + 1) * m] * ww[c + 1];
            a2 += tp[(c + 2) * m] * ww[c + 2];
            a3 += tp[(c + 3) * m] * ww[c + 3];
        }
        acc = (a0 + a1) + (a2 + a3);
    }
    if (p < KST) V[(size_t)o * KST + p] = __float2bfloat16(acc);
}

// ---------------------------------------------------------------------------
// Kernel B: X[n, s*25+alpha] = sk[n,s] * ang[n,alpha], bf16, padded to KST.
// ---------------------------------------------------------------------------
__global__ void build_X(const float* __restrict__ sk,
                        const float* __restrict__ ang,
                        __hip_bfloat16* __restrict__ X)
{
    const int idx = blockIdx.x * 256 + threadIdx.x;
    if (idx >= N_ROWS * (KST / 8)) return;
    const int n  = idx / (KST / 8);
    const int p0 = (idx - n * (KST / 8)) * 8;
    const float* skn  = sk  + (size_t)n * SB;
    const float* angn = ang + (size_t)n * ANGD;
    alignas(16) __hip_bfloat16 tmp[8];
    #pragma unroll
    for (int u = 0; u < 8; ++u) {
        const int p = p0 + u;
        float v = 0.f;
        if (p < PDIM) {
            const int s = p / ANGD;
            const int a = p - s * ANGD;
            v = skn[s] * angn[a];
        }
        tmp[u] = __float2bfloat16(v);
    }
    *(bf16x8*)(X + (size_t)n * KST + p0) = *(const bf16x8*)tmp;
}

// ---------------------------------------------------------------------------
// Kernel C: 128x128-tile bf16 GEMM, write-bound K=320 regime.
// Inner loop identical to rounds 7-8. NEW: epilogue routes the C tile
// through LDS ([64][132] f32, two passes) so each wave-store is 2x512 B
// contiguous (full 128B lines) instead of 16 scattered 64 B segments.
// ---------------------------------------------------------------------------
__global__ __launch_bounds__(512, 4) void gemm_bt(
    const __hip_bfloat16* __restrict__ A,   // X: (N_ROWS, KST)
    const __hip_bfloat16* __restrict__ B,   // V: (OPAD, KST)
    float* __restrict__ C)
{
    __shared__ __align__(1024) char lds[65536];
    char* const bufA = lds;            // 2 x 16384 B
    char* const bufB = lds + 32768;    // 2 x 16384 B
    float* const s_c = (float*)lds;    // epilogue alias: [64][132] f32

    const int tid  = threadIdx.x;
    const int wave = tid >> 6;
    const int lane = tid & 63;

    const int bn = blockIdx.x;         // 22 col tiles
    const int bm = blockIdx.y;         // 250 row tiles
    const size_t arow0 = (size_t)bm * 128;
    const size_t brow0 = (size_t)bn * 128;

    const int wr = wave >> 2;   // 0..1 (M half: 64 rows)
    const int wc = wave & 3;    // 0..3 (N quarter: 32 cols)

    // staging lane constants (LDS linear dest; global source pre-swizzled)
    const int lrow  = lane >> 3;
    const int lslot = ((lane & 7) ^ (lrow & 7)) << 4;

    auto STAGE = [&](const char* gbase, size_t growbase, int t, char* lbase) {
        const char* g0 = gbase + (growbase + (size_t)(wave * 8 + lrow)) * (KST * 2)
                               + (size_t)t * 128 + lslot;
        gload16(g0,                          lbase + wave * 1024);
        gload16(g0 + (size_t)64 * (KST * 2), lbase + 8192 + wave * 1024);
    };

    // reader lane constants (swizzle: slot = (ks*4+koct) ^ (row&7))
    const int rl   = lane & 15;
    const int koct = lane >> 4;
    const int sK0 = ((0 * 4 + koct) ^ (lane & 7)) << 4;
    const int sK1 = ((1 * 4 + koct) ^ (lane & 7)) << 4;

    // prologue: stage t0 into buf0, t1 into buf1
    STAGE((const char*)A, arow0, 0, bufA + 0);
    STAGE((const char*)B, brow0, 0, bufB + 0);
    STAGE((const char*)A, arow0, 1, bufA + 16384);
    STAGE((const char*)B, brow0, 1, bufB + 16384);
    asm volatile("s_waitcnt vmcnt(4)" ::: "memory");
    __builtin_amdgcn_s_barrier();

    f32x4 acc[4][2] = {};   // [m][n]; D^T frags: row=o, col=M

    for (int t = 0; t < NT; ++t) {
        char* const aC = bufA + (t & 1) * 16384;
        char* const bC = bufB + (t & 1) * 16384;

        bf16x8 af[4][2], bfr[2][2];
        #pragma unroll
        for (int m = 0; m < 4; ++m) {
            const int r = wr * 64 + m * 16 + rl;
            af[m][0] = *(const bf16x8*)(aC + r * 128 + sK0);
            af[m][1] = *(const bf16x8*)(aC + r * 128 + sK1);
        }
        #pragma unroll
        for (int n = 0; n < 2; ++n) {
            const int r = wc * 32 + n * 16 + rl;
            bfr[n][0] = *(const bf16x8*)(bC + r * 128 + sK0);
            bfr[n][1] = *(const bf16x8*)(bC + r * 128 + sK1);
        }
        asm volatile("s_waitcnt lgkmcnt(0)" ::: "memory");
        __builtin_amdgcn_sched_barrier(0);
        __builtin_amdgcn_s_barrier();   // all waves done reading this buf

        if (t + 2 < NT) {               // stage t+2 into the buffer just read
            STAGE((const char*)A, arow0, t + 2, aC);
            STAGE((const char*)B, brow0, t + 2, bC);
        }

        __builtin_amdgcn_s_setprio(1);
        #pragma unroll
        for (int ks = 0; ks < 2; ++ks)
            #pragma unroll
            for (int m = 0; m < 4; ++m)
                #pragma unroll
                for (int n = 0; n < 2; ++n)
                    acc[m][n] = __builtin_amdgcn_mfma_f32_16x16x32_bf16(
                        bfr[n][ks], af[m][ks], acc[m][n], 0, 0, 0);
        __builtin_amdgcn_s_setprio(0);
        __builtin_amdgcn_sched_barrier(0);

        if (t < NT - 2)       asm volatile("s_waitcnt vmcnt(4)" ::: "memory");
        else if (t == NT - 2) asm volatile("s_waitcnt vmcnt(0)" ::: "memory");
        if (t < NT - 1) __builtin_amdgcn_s_barrier();
    }

    // ---- epilogue through LDS: two 64-row passes, full-line stores ----
    // acc[m][n] = 4 consecutive o at fixed M:
    //   M = arow0 + wr*64 + m*16 + rl,  o = brow0 + wc*32 + n*16 + koct*4
    #pragma unroll
    for (int h = 0; h < 2; ++h) {
        __syncthreads();   // previous pass reads (or K-loop LDS reads) done
        if (wr == h) {
            #pragma unroll
            for (int m = 0; m < 4; ++m) {
                const int row_l = m * 16 + rl;             // 0..63
                #pragma unroll
                for (int n = 0; n < 2; ++n) {
                    const int col = wc * 32 + n * 16 + koct * 4;   // 0..124
                    *(f32x4*)&s_c[row_l * 132 + col] = acc[m][n];
                }
            }
        }
        __syncthreads();
        // read back linearly: 64 rows x 32 f32x4-groups = 2048 groups
        #pragma unroll
        for (int rr = 0; rr < 4; ++rr) {
            const int idx  = rr * 512 + tid;
            const int row  = idx >> 5;
            const int g4   = (idx & 31) * 4;
            if ((int)brow0 + g4 < OCOLS) {
                const f32x4 v = *(const f32x4*)&s_c[row * 132 + g4];
                __builtin_nontemporal_store(v,
                    (f32x4*)(C + (size_t)(arow0 + h * 64 + row) * OCOLS + brow0 + g4));
            }
        }
    }
}

// ---------------------------------------------------------------------------
extern "C" void kernel_launch(void* const* d_in, const int* in_sizes, int n_in,
                              void* d_out, int out_size, void* d_ws, size_t ws_size,
                              hipStream_t stream)
{
    const float* sk  = (const float*)d_in[0];   // (16,16,125,12)
    const float* ang = (const float*)d_in[1];   // (32000,25)
    const float* W   = (const float*)d_in[2];   // (12,720)
    const float* TP  = (const float*)d_in[3];   // (2704,2704)
    float* out = (float*)d_out;                 // (32000,2704)

    __hip_bfloat16* X  = (__hip_bfloat16*)d_ws;             // N_ROWS*KST bf16 (20.5 MB)
    __hip_bfloat16* Vb = X + (size_t)N_ROWS * KST;          // OPAD*KST bf16 (1.8 MB)

    build_V<<<OPAD, 320, 0, stream>>>(TP, W, Vb);
    build_X<<<(N_ROWS * (KST / 8) + 255) / 256, 256, 0, stream>>>(sk, ang, X);

    dim3 grid(OPAD / 128, N_ROWS / 128);   // (22, 250)
    gemm_bt<<<grid, 512, 0, stream>>>(X, Vb, out);
}